// Round 1
// baseline (364.850 us; speedup 1.0000x reference)
//
#include <hip/hip_runtime.h>
#include <hip/hip_bf16.h>

typedef __attribute__((ext_vector_type(8))) short s16x8;
typedef __attribute__((ext_vector_type(4))) float f32x4;

__device__ inline float bf2f(unsigned short u) {
  union { unsigned int i; float f; } v; v.i = ((unsigned int)u) << 16; return v.f;
}
__device__ inline unsigned short f2bf(float f) {
  union { float f; unsigned int i; } v; v.f = f;
  unsigned int r = (v.i + 0x7FFFu + ((v.i >> 16) & 1u)) >> 16;
  return (unsigned short)r;
}
__device__ inline void gl_lds16(const void* g, void* l) {
  __builtin_amdgcn_global_load_lds(
      (const __attribute__((address_space(1))) unsigned int*)g,
      (__attribute__((address_space(3))) unsigned int*)l, 16, 0, 0);
}

// ---------------- elementwise cast x -> bf16 ----------------
__global__ __launch_bounds__(256) void cast_to_bf16(const float* __restrict__ s,
                                                    unsigned short* __restrict__ d, int n4) {
  int i = blockIdx.x * 256 + threadIdx.x;
  if (i >= n4) return;
  float4 v = ((const float4*)s)[i];
  ushort4 o;
  o.x = f2bf(v.x); o.y = f2bf(v.y); o.z = f2bf(v.z); o.w = f2bf(v.w);
  ((ushort4*)d)[i] = o;
}

// ---------------- transpose + cast weight: src[K][N] f32 -> dst[N][K] bf16 ----------------
__global__ __launch_bounds__(256) void transpose_cast(const float* __restrict__ src,
                                                      unsigned short* __restrict__ dst,
                                                      int K, int N) {
  __shared__ float tile[32][33];
  int n0 = blockIdx.x * 32, k0 = blockIdx.y * 32;
  int tx = threadIdx.x & 31, ty = threadIdx.x >> 5;
#pragma unroll
  for (int i = 0; i < 4; ++i) {
    int k = ty + i * 8;
    tile[k][tx] = src[(size_t)(k0 + k) * N + n0 + tx];
  }
  __syncthreads();
#pragma unroll
  for (int i = 0; i < 4; ++i) {
    int n = ty + i * 8;
    dst[(size_t)(n0 + n) * K + k0 + tx] = f2bf(tile[tx][n]);
  }
}

// ---------------- RoPE tables ----------------
__global__ __launch_bounds__(256) void rope_tables(float* __restrict__ ct, float* __restrict__ st) {
  int idx = blockIdx.x * 256 + threadIdx.x;  // 2048*64
  int s = idx >> 6, i = idx & 63;
  float inv = powf(10000.0f, -(float)(2 * i) * (1.0f / 128.0f));
  float ang = (float)s * inv;
  ct[idx] = cosf(ang);
  st[idx] = sinf(ang);
}

// ---------------- RoPE apply in place on Q (16 heads) and K (4 heads) ----------------
__global__ __launch_bounds__(256) void rope_apply(unsigned short* __restrict__ qkv,
                                                  const float* __restrict__ ct,
                                                  const float* __restrict__ st) {
  int row = blockIdx.x;  // 0..4095 = b*2048+s
  int pos = row & 2047;
  unsigned short* base = qkv + (size_t)row * 3072;
  for (int it = threadIdx.x; it < 1280; it += 256) {  // 20 heads * 64 half-dims
    int head = it >> 6, dh = it & 63;
    int col = head < 16 ? head * 128 : 2048 + (head - 16) * 128;
    float a = bf2f(base[col + dh]);
    float b = bf2f(base[col + dh + 64]);
    float c = ct[pos * 64 + dh], sn = st[pos * 64 + dh];
    base[col + dh] = f2bf(a * c - b * sn);
    base[col + dh + 64] = f2bf(b * c + a * sn);
  }
}

// ---------------- GEMM: C[M,N] = A[M,K] * BT[N,K]^T  (all bf16 in, f32 acc) ----------------
template <int BF16OUT>
__global__ __launch_bounds__(256) void gemm_bt(const unsigned short* __restrict__ A,
                                               const unsigned short* __restrict__ BT,
                                               void* __restrict__ Cv,
                                               int M, int N, int K) {
  __shared__ __align__(16) unsigned short Al[128 * 64];
  __shared__ __align__(16) unsigned short Bl[128 * 64];
  const int t = threadIdx.x, lane = t & 63, w = t >> 6;
  const int m16 = lane & 15, l4 = lane >> 4;
  const int wr = (w >> 1) * 64, wc = (w & 1) * 64;
  const int rowBase = blockIdx.y * 128, colBase = blockIdx.x * 128;
  f32x4 acc[4][4];
#pragma unroll
  for (int mi = 0; mi < 4; ++mi)
#pragma unroll
    for (int ni = 0; ni < 4; ++ni) {
      f32x4 z = {0.f, 0.f, 0.f, 0.f};
      acc[mi][ni] = z;
    }
  for (int k0 = 0; k0 < K; k0 += 64) {
    __syncthreads();  // protect LDS from overwrite while others compute
#pragma unroll
    for (int i = 0; i < 4; ++i) {
      int c = (i * 4 + w) * 64 + lane;   // 0..1023 chunks of 16B
      int r = c >> 3, ch = c & 7;        // 8 chunks per 64-elem row
      gl_lds16(A + (size_t)(rowBase + r) * K + k0 + ch * 8, (char*)Al + c * 16);
      gl_lds16(BT + (size_t)(colBase + r) * K + k0 + ch * 8, (char*)Bl + c * 16);
    }
    __syncthreads();
#pragma unroll
    for (int kc = 0; kc < 2; ++kc) {
      s16x8 af[4], bf[4];
#pragma unroll
      for (int mi = 0; mi < 4; ++mi)
        af[mi] = *(const s16x8*)&Al[(wr + mi * 16 + m16) * 64 + kc * 32 + l4 * 8];
#pragma unroll
      for (int ni = 0; ni < 4; ++ni)
        bf[ni] = *(const s16x8*)&Bl[(wc + ni * 16 + m16) * 64 + kc * 32 + l4 * 8];
#pragma unroll
      for (int mi = 0; mi < 4; ++mi)
#pragma unroll
        for (int ni = 0; ni < 4; ++ni)
          acc[mi][ni] = __builtin_amdgcn_mfma_f32_16x16x32_bf16(af[mi], bf[ni], acc[mi][ni], 0, 0, 0);
    }
  }
#pragma unroll
  for (int mi = 0; mi < 4; ++mi)
#pragma unroll
    for (int ni = 0; ni < 4; ++ni) {
      int r0 = rowBase + wr + mi * 16 + l4 * 4;
      int c0 = colBase + wc + ni * 16 + m16;
#pragma unroll
      for (int jr = 0; jr < 4; ++jr) {
        if (BF16OUT)
          ((unsigned short*)Cv)[(size_t)(r0 + jr) * N + c0] = f2bf(acc[mi][ni][jr]);
        else
          ((float*)Cv)[(size_t)(r0 + jr) * N + c0] = acc[mi][ni][jr];
      }
    }
}

// ---------------- flash attention (non-causal, GQA rep=4) ----------------
// qkv rows: [b*2048+s][3072] = Q(16*128) | K(4*128) | V(4*128), post-RoPE bf16.
// Block: 4 waves x 16 q-rows = 64 q-rows. KV tile = 64.
__global__ __launch_bounds__(256) void attn_kernel(const unsigned short* __restrict__ qkv,
                                                   unsigned short* __restrict__ obuf) {
  __shared__ __align__(16) unsigned short Klds[64 * 128];   // row-XOR-swizzled content
  __shared__ __align__(16) unsigned short Vt[128 * 64];     // V^T with col XOR swizzle
  __shared__ __align__(16) unsigned short Plds[4][16 * 64]; // per-wave P
  const int t = threadIdx.x, lane = t & 63, w = t >> 6;
  const int m16 = lane & 15, l4 = lane >> 4;
  const int b = blockIdx.z, h = blockIdx.y, qb = blockIdx.x;
  const int kvh = h >> 2;
  const float scale = 0.08838834764831845f;  // 1/sqrt(128)

  // Q fragments: lane holds Q[q=l&15][dc*32 + l4*8 + j]
  s16x8 qf[4];
  const unsigned short* qp =
      qkv + (size_t)(b * 2048 + qb * 64 + w * 16 + m16) * 3072 + h * 128 + l4 * 8;
#pragma unroll
  for (int dc = 0; dc < 4; ++dc) qf[dc] = *(const s16x8*)(qp + dc * 32);

  float mrow[4], lsum[4];
  f32x4 acco[8];
#pragma unroll
  for (int jr = 0; jr < 4; ++jr) { mrow[jr] = -1e30f; lsum[jr] = 0.f; }
#pragma unroll
  for (int df = 0; df < 8; ++df) {
    f32x4 z = {0.f, 0.f, 0.f, 0.f};
    acco[df] = z;
  }

  const unsigned short* kbase = qkv + (size_t)(b * 2048) * 3072 + 2048 + kvh * 128;
  const unsigned short* vbase = qkv + (size_t)(b * 2048) * 3072 + 2560 + kvh * 128;

  for (int kt = 0; kt < 32; ++kt) {
    // ---- stage K tile via global_load_lds, pre-swizzled source ----
#pragma unroll
    for (int i = 0; i < 4; ++i) {
      int c = (i * 4 + w) * 64 + lane;  // 1024 chunks: 64 rows x 16 chunks
      int row = c >> 4, ch = c & 15;
      const char* src = (const char*)(kbase + (size_t)(kt * 64 + row) * 3072) +
                        ((ch * 16) ^ ((row & 7) << 4));
      gl_lds16(src, (char*)Klds + c * 16);
    }
    // ---- stage V transposed (register path, XOR col swizzle) ----
#pragma unroll
    for (int r = 0; r < 4; ++r) {
      int sv = r * 16 + (t >> 4);
      int d0 = (t & 15) * 8;
      s16x8 v8 = *(const s16x8*)(vbase + (size_t)(kt * 64 + sv) * 3072 + d0);
#pragma unroll
      for (int j = 0; j < 8; ++j) {
        int dd = d0 + j;
        int sw = ((dd ^ (dd >> 3)) & 7) << 3;
        Vt[dd * 64 + (sv ^ sw)] = (unsigned short)v8[j];
      }
    }
    __syncthreads();
    // ---- S = Q K^T : frags D[q][kk], rows q=(l4*4+jr), col kk=kkt*16+m16 ----
    f32x4 sc[4];
#pragma unroll
    for (int kkt = 0; kkt < 4; ++kkt) {
      f32x4 a = {0.f, 0.f, 0.f, 0.f};
#pragma unroll
      for (int dc = 0; dc < 4; ++dc) {
        int row = kkt * 16 + m16;
        int off = row * 256 + ((dc * 64 + l4 * 16) ^ ((row & 7) << 4));
        s16x8 kf = *(const s16x8*)((const char*)Klds + off);
        a = __builtin_amdgcn_mfma_f32_16x16x32_bf16(qf[dc], kf, a, 0, 0, 0);
      }
      sc[kkt] = a;
    }
#pragma unroll
    for (int kkt = 0; kkt < 4; ++kkt) sc[kkt] *= scale;
    // ---- online softmax (per-row stats shared by the 16-lane group) ----
    float rs[4];
#pragma unroll
    for (int jr = 0; jr < 4; ++jr) {
      float v = fmaxf(fmaxf(sc[0][jr], sc[1][jr]), fmaxf(sc[2][jr], sc[3][jr]));
#pragma unroll
      for (int off = 1; off < 16; off <<= 1) v = fmaxf(v, __shfl_xor(v, off));
      float mn = fmaxf(mrow[jr], v);
      rs[jr] = __expf(mrow[jr] - mn);
      mrow[jr] = mn;
    }
#pragma unroll
    for (int df = 0; df < 8; ++df) {
      f32x4 o = acco[df];
      o[0] *= rs[0]; o[1] *= rs[1]; o[2] *= rs[2]; o[3] *= rs[3];
      acco[df] = o;
    }
#pragma unroll
    for (int jr = 0; jr < 4; ++jr) {
      float part = 0.f;
#pragma unroll
      for (int kkt = 0; kkt < 4; ++kkt) {
        float p = __expf(sc[kkt][jr] - mrow[jr]);
        part += p;
        Plds[w][(l4 * 4 + jr) * 64 + kkt * 16 + m16] = f2bf(p);
      }
      lsum[jr] = lsum[jr] * rs[jr] + part;
    }
    // ---- O += P V : A-frag of P from LDS round-trip, B-frag of V from Vt ----
    s16x8 ap[2];
#pragma unroll
    for (int kc = 0; kc < 2; ++kc)
      ap[kc] = *(const s16x8*)&Plds[w][m16 * 64 + kc * 32 + l4 * 8];
#pragma unroll
    for (int df = 0; df < 8; ++df) {
      int dcol = df * 16 + m16;
      int sw = ((dcol ^ (dcol >> 3)) & 7) << 3;
#pragma unroll
      for (int kc = 0; kc < 2; ++kc) {
        s16x8 vf = *(const s16x8*)&Vt[dcol * 64 + ((kc * 32 + l4 * 8) ^ sw)];
        acco[df] = __builtin_amdgcn_mfma_f32_16x16x32_bf16(ap[kc], vf, acco[df], 0, 0, 0);
      }
    }
    __syncthreads();
  }
  // ---- finalize ----
  float inv[4];
#pragma unroll
  for (int jr = 0; jr < 4; ++jr) {
    float v = lsum[jr];
#pragma unroll
    for (int off = 1; off < 16; off <<= 1) v += __shfl_xor(v, off);
    inv[jr] = 1.0f / v;
  }
  unsigned short* op =
      obuf + (size_t)(b * 2048 + qb * 64 + w * 16 + l4 * 4) * 2048 + h * 128 + m16;
#pragma unroll
  for (int df = 0; df < 8; ++df)
#pragma unroll
    for (int jr = 0; jr < 4; ++jr)
      op[(size_t)jr * 2048 + df * 16] = f2bf(acco[df][jr] * inv[jr]);
}

extern "C" void kernel_launch(void* const* d_in, const int* in_sizes, int n_in,
                              void* d_out, int out_size, void* d_ws, size_t ws_size,
                              hipStream_t stream) {
  (void)in_sizes; (void)n_in; (void)out_size; (void)ws_size;
  const float* x  = (const float*)d_in[0];
  const float* wq = (const float*)d_in[1];
  const float* wk = (const float*)d_in[2];
  const float* wv = (const float*)d_in[3];
  const float* wo = (const float*)d_in[4];

  char* ws = (char*)d_ws;
  unsigned short* xb    = (unsigned short*)(ws);              // 4096x2048 bf16 (16.78 MB)
  unsigned short* wqkvT = (unsigned short*)(ws + 16777216);   // 3072x2048 bf16 (12.58 MB)
  unsigned short* woT   = (unsigned short*)(ws + 29360128);   // 2048x2048 bf16 (8.39 MB)
  unsigned short* qkv   = (unsigned short*)(ws + 37748736);   // 4096x3072 bf16 (25.17 MB)
  unsigned short* obuf  = (unsigned short*)(ws + 62914560);   // 4096x2048 bf16 (16.78 MB)
  float* ct             = (float*)(ws + 79691776);            // 2048x64 f32
  float* st             = (float*)(ws + 80216064);            // 2048x64 f32

  cast_to_bf16<<<8192, 256, 0, stream>>>(x, xb, 2097152);
  transpose_cast<<<dim3(64, 64), 256, 0, stream>>>(wq, wqkvT, 2048, 2048);
  transpose_cast<<<dim3(16, 64), 256, 0, stream>>>(wk, wqkvT + 2048 * 2048, 2048, 512);
  transpose_cast<<<dim3(16, 64), 256, 0, stream>>>(wv, wqkvT + 2560 * 2048, 2048, 512);
  transpose_cast<<<dim3(64, 64), 256, 0, stream>>>(wo, woT, 2048, 2048);
  rope_tables<<<512, 256, 0, stream>>>(ct, st);
  gemm_bt<1><<<dim3(24, 32), 256, 0, stream>>>(xb, wqkvT, qkv, 4096, 3072, 2048);
  rope_apply<<<4096, 256, 0, stream>>>(qkv, ct, st);
  attn_kernel<<<dim3(32, 16, 2), 256, 0, stream>>>(qkv, obuf);
  gemm_bt<0><<<dim3(16, 32), 256, 0, stream>>>(obuf, woT, d_out, 4096, 2048, 2048);
}